// Round 3
// baseline (1134.710 us; speedup 1.0000x reference)
//
#include <hip/hip_runtime.h>
#include <hip/hip_bf16.h>
#include <math.h>

#define D_INF 128
#define HF    256
#define LF    3

typedef float f32x4 __attribute__((ext_vector_type(4)));
typedef short bf16x8 __attribute__((ext_vector_type(8)));

// round-to-nearest-even f32 -> bf16 (returned as short bit pattern) and the
// rounded value as f32 (for residual computation)
__device__ inline void rne_bf16(float x, short& h, float& hf) {
    uint32_t u = __float_as_uint(x);
    uint32_t r = u + 0x7FFFu + ((u >> 16) & 1u);
    r &= 0xFFFF0000u;
    h = (short)(r >> 16);
    hf = __uint_as_float(r);
}

// ---------------------------------------------------------------------------
// Generic f32 GEMM: C[M,N] = A[M,K] @ B[K,N] (+ optional bias[N])
// tile 64x64, 256 threads, per-thread 4x4, K-step 16
// Used for: input projection, P1 = h@W1a, P2 = h@W1b
// ---------------------------------------------------------------------------
__global__ __launch_bounds__(256) void gemm_f32(
    const float* __restrict__ A, const float* __restrict__ B,
    const float* __restrict__ bias, float* __restrict__ C,
    int M, int K, int N)
{
    __shared__ __align__(16) float As[16][68];
    __shared__ __align__(16) float Bs[16][68];
    const int tid = threadIdx.x;
    const int tx = tid & 15, ty = tid >> 4;
    const int row0 = blockIdx.x * 64;
    const int col0 = blockIdx.y * 64;
    float acc[4][4] = {};

    for (int k0 = 0; k0 < K; k0 += 16) {
        {
            int m = tid >> 2, kk4 = (tid & 3) << 2;
            int gr = row0 + m;
            float4 v = make_float4(0.f, 0.f, 0.f, 0.f);
            if (gr < M) v = *(const float4*)(A + (size_t)gr * K + k0 + kk4);
            As[kk4 + 0][m] = v.x;
            As[kk4 + 1][m] = v.y;
            As[kk4 + 2][m] = v.z;
            As[kk4 + 3][m] = v.w;
        }
        {
            int kk = tid >> 4, n4 = (tid & 15) << 2;
            float4 v = *(const float4*)(B + (size_t)(k0 + kk) * N + col0 + n4);
            *(float4*)&Bs[kk][n4] = v;
        }
        __syncthreads();
        #pragma unroll
        for (int kk = 0; kk < 16; kk++) {
            float a4[4], b4[4];
            *(float4*)a4 = *(const float4*)&As[kk][ty << 2];
            *(float4*)b4 = *(const float4*)&Bs[kk][tx << 2];
            #pragma unroll
            for (int i = 0; i < 4; i++)
                #pragma unroll
                for (int j = 0; j < 4; j++)
                    acc[i][j] += a4[i] * b4[j];
        }
        __syncthreads();
    }

    int c = col0 + (tx << 2);
    #pragma unroll
    for (int i = 0; i < 4; i++) {
        int r = row0 + (ty << 2) + i;
        if (r >= M) continue;
        float4 o;
        o.x = acc[i][0]; o.y = acc[i][1]; o.z = acc[i][2]; o.w = acc[i][3];
        if (bias) {
            o.x += bias[c + 0]; o.y += bias[c + 1];
            o.z += bias[c + 2]; o.w += bias[c + 3];
        }
        *(float4*)(C + (size_t)r * N + c) = o;
    }
}

// ---------------------------------------------------------------------------
// f32 fused MLP-to-scalar (fallback edge path + eps path):
// out[r] = relu(A[r]@B + b1 [+ P1[src[r]] + P2[dst[r]]]) . w2 + b2
// ---------------------------------------------------------------------------
__global__ __launch_bounds__(256) void mlp_score_kernel(
    const float* __restrict__ A, const float* __restrict__ B,
    const float* __restrict__ b1, const float* __restrict__ w2,
    const float* __restrict__ b2,
    const float* __restrict__ P1, const float* __restrict__ P2,
    const int* __restrict__ src, const int* __restrict__ dst,
    float* __restrict__ out, int M, int K)
{
    __shared__ __align__(16) float As[16][68];
    __shared__ __align__(16) float Bs[16][260];
    const int tid = threadIdx.x;
    const int tx = tid & 15, ty = tid >> 4;
    const int row0 = blockIdx.x * 64;
    float acc[4][16] = {};

    for (int k0 = 0; k0 < K; k0 += 16) {
        {
            int m = tid >> 2, kk4 = (tid & 3) << 2;
            int gr = row0 + m;
            float4 v = make_float4(0.f, 0.f, 0.f, 0.f);
            if (gr < M) v = *(const float4*)(A + (size_t)gr * K + k0 + kk4);
            As[kk4 + 0][m] = v.x;
            As[kk4 + 1][m] = v.y;
            As[kk4 + 2][m] = v.z;
            As[kk4 + 3][m] = v.w;
        }
        {
            int kk = ty;
            int cb = tx << 4;
            const float* bp = B + (size_t)(k0 + kk) * HF + cb;
            *(float4*)&Bs[kk][cb +  0] = *(const float4*)(bp +  0);
            *(float4*)&Bs[kk][cb +  4] = *(const float4*)(bp +  4);
            *(float4*)&Bs[kk][cb +  8] = *(const float4*)(bp +  8);
            *(float4*)&Bs[kk][cb + 12] = *(const float4*)(bp + 12);
        }
        __syncthreads();
        #pragma unroll
        for (int kk = 0; kk < 16; kk++) {
            float a4[4];
            *(float4*)a4 = *(const float4*)&As[kk][ty << 2];
            float b16[16];
            #pragma unroll
            for (int cb = 0; cb < 4; cb++)
                *(float4*)&b16[cb * 4] = *(const float4*)&Bs[kk][cb * 64 + (tx << 2)];
            #pragma unroll
            for (int i = 0; i < 4; i++)
                #pragma unroll
                for (int j = 0; j < 16; j++)
                    acc[i][j] += a4[i] * b16[j];
        }
        __syncthreads();
    }

    float b1v[16], w2v[16];
    #pragma unroll
    for (int cb = 0; cb < 4; cb++) {
        *(float4*)&b1v[cb * 4] = *(const float4*)(b1 + cb * 64 + (tx << 2));
        *(float4*)&w2v[cb * 4] = *(const float4*)(w2 + cb * 64 + (tx << 2));
    }
    const float bias2 = b2[0];

    #pragma unroll
    for (int i = 0; i < 4; i++) {
        int r = row0 + (ty << 2) + i;
        if (r < M) {
            float p = 0.f;
            if (P1) {
                const float* p1 = P1 + (size_t)src[r] * HF;
                const float* p2 = P2 + (size_t)dst[r] * HF;
                #pragma unroll
                for (int cb = 0; cb < 4; cb++) {
                    float g1[4], g2[4];
                    *(float4*)g1 = *(const float4*)(p1 + cb * 64 + (tx << 2));
                    *(float4*)g2 = *(const float4*)(p2 + cb * 64 + (tx << 2));
                    #pragma unroll
                    for (int j = 0; j < 4; j++) {
                        float v = acc[i][cb * 4 + j] + g1[j] + g2[j] + b1v[cb * 4 + j];
                        p += fmaxf(v, 0.f) * w2v[cb * 4 + j];
                    }
                }
            } else {
                #pragma unroll
                for (int j = 0; j < 16; j++) {
                    float v = acc[i][j] + b1v[j];
                    p += fmaxf(v, 0.f) * w2v[j];
                }
            }
            #pragma unroll
            for (int o = 8; o > 0; o >>= 1) p += __shfl_down(p, o, 16);
            if (tx == 0) out[r] = p + bias2;
        }
    }
}

// ---------------------------------------------------------------------------
// Weight prep for MFMA edge path: W1c (rows 512..767 of a_w1[l]) ->
// transposed [c][k], split hi/lo bf16, chunk-major and LDS-image pre-swizzled:
// dest idx = ((l*8 + k/32)*256 + c)*32 + ( ((k>>3)&3) ^ ((c>>2)&3) )*8 + (k&7)
// ---------------------------------------------------------------------------
__global__ void conv_w1cT_kernel(const float* __restrict__ a_w1,
                                 short* __restrict__ WhiT, short* __restrict__ WloT)
{
    int t = blockIdx.x * blockDim.x + threadIdx.x;
    if (t >= LF * HF * HF) return;
    int c  = t & 255;
    int k  = (t >> 8) & 255;
    int ly = t >> 16;
    float x = a_w1[((size_t)ly * 3 * HF + 2 * HF + k) * HF + c];
    short hh, ll; float hf, lf_;
    rne_bf16(x, hh, hf);
    rne_bf16(x - hf, ll, lf_);
    int ck = k >> 5;
    int j  = ((((k >> 3) & 3) ^ ((c >> 2) & 3)) << 3) + (k & 7);
    size_t d = (((size_t)ly * 8 + ck) * 256 + c) * 32 + j;
    WhiT[d] = hh;
    WloT[d] = ll;
}

// ---------------------------------------------------------------------------
// MFMA edge-score kernel (split-bf16, fp32-accurate):
// a[e] = relu(gh[e]@W1c + P1[src] + P2[dst] + b1) . w2 + b2
// Block: 64 edges x 256 cols, 4 waves (wave = 64 rows x 64 cols),
// per wave 4x4 tiles of 16x16, K-chunks of 32, 3 MFMAs per tile-chunk.
// ---------------------------------------------------------------------------
__global__ __launch_bounds__(256) void edge_mfma_kernel(
    const float* __restrict__ gh,
    const short* __restrict__ WhiT, const short* __restrict__ WloT,
    const float* __restrict__ b1, const float* __restrict__ w2,
    const float* __restrict__ b2,
    const float* __restrict__ P1, const float* __restrict__ P2,
    const int* __restrict__ src, const int* __restrict__ dst,
    float* __restrict__ out)
{
    __shared__ __align__(16) short Ahi[64 * 32];    // 4 KB
    __shared__ __align__(16) short Alo[64 * 32];    // 4 KB
    __shared__ __align__(16) short Bhi[256 * 32];   // 16 KB
    __shared__ __align__(16) short Blo[256 * 32];   // 16 KB
    __shared__ float part[64][4];

    const int tid = threadIdx.x;
    const int w   = tid >> 6;    // wave 0..3 -> col quarter
    const int l   = tid & 63;
    const int g   = l >> 4;      // k-group within wave
    const int e0  = blockIdx.x * 64;

    const f32x4 zero4 = {0.f, 0.f, 0.f, 0.f};
    f32x4 acc[4][4];
    #pragma unroll
    for (int i = 0; i < 4; i++)
        #pragma unroll
        for (int j = 0; j < 4; j++)
            acc[i][j] = zero4;

    for (int ck = 0; ck < 8; ck++) {
        const int k0 = ck * 32;
        // ---- stage B: direct copy of pre-swizzled 16KB images ----
        {
            const short* sHi = WhiT + (size_t)ck * (256 * 32);
            const short* sLo = WloT + (size_t)ck * (256 * 32);
            #pragma unroll
            for (int p = 0; p < 4; p++) {
                int off8 = (p * 256 + tid) * 8;
                *(bf16x8*)&Bhi[off8] = *(const bf16x8*)&sHi[off8];
                *(bf16x8*)&Blo[off8] = *(const bf16x8*)&sLo[off8];
            }
        }
        // ---- stage A: load f32, split hi/lo, swizzled ds_write ----
        {
            const int r = tid >> 2, p = tid & 3;
            const float* gp = gh + (size_t)(e0 + r) * HF + k0 + p * 8;
            float vf[8];
            *(float4*)&vf[0] = *(const float4*)gp;
            *(float4*)&vf[4] = *(const float4*)(gp + 4);
            bf16x8 hv, lv;
            #pragma unroll
            for (int j = 0; j < 8; j++) {
                short hh, ll; float hf, lf_;
                rne_bf16(vf[j], hh, hf);
                rne_bf16(vf[j] - hf, ll, lf_);
                hv[j] = hh;
                lv[j] = ll;
            }
            const int s = p ^ ((r >> 2) & 3);
            *(bf16x8*)&Ahi[(r * 4 + s) * 8] = hv;
            *(bf16x8*)&Alo[(r * 4 + s) * 8] = lv;
        }
        __syncthreads();

        // ---- fragments + MFMA ----
        bf16x8 ah[4], al[4];
        #pragma unroll
        for (int rt = 0; rt < 4; rt++) {
            int r = rt * 16 + (l & 15);
            int s = g ^ ((r >> 2) & 3);
            ah[rt] = *(const bf16x8*)&Ahi[(r * 4 + s) * 8];
            al[rt] = *(const bf16x8*)&Alo[(r * 4 + s) * 8];
        }
        #pragma unroll
        for (int ct = 0; ct < 4; ct++) {
            int c = w * 64 + ct * 16 + (l & 15);
            int s = g ^ ((c >> 2) & 3);
            bf16x8 bh = *(const bf16x8*)&Bhi[(c * 4 + s) * 8];
            bf16x8 bl = *(const bf16x8*)&Blo[(c * 4 + s) * 8];
            #pragma unroll
            for (int rt = 0; rt < 4; rt++) {
                acc[rt][ct] = __builtin_amdgcn_mfma_f32_16x16x32_bf16(ah[rt], bh, acc[rt][ct], 0, 0, 0);
                acc[rt][ct] = __builtin_amdgcn_mfma_f32_16x16x32_bf16(al[rt], bh, acc[rt][ct], 0, 0, 0);
                acc[rt][ct] = __builtin_amdgcn_mfma_f32_16x16x32_bf16(ah[rt], bl, acc[rt][ct], 0, 0, 0);
            }
        }
        __syncthreads();
    }

    // ---- fused epilogue: gather + relu + dot(w2) + reduce ----
    float w2v[4], b1v[4];
    #pragma unroll
    for (int ct = 0; ct < 4; ct++) {
        int c = w * 64 + ct * 16 + (l & 15);
        w2v[ct] = w2[c];
        b1v[ct] = b1[c];
    }
    #pragma unroll
    for (int rt = 0; rt < 4; rt++) {
        #pragma unroll
        for (int i = 0; i < 4; i++) {
            int r = rt * 16 + g * 4 + i;   // C/D layout: row=(lane>>4)*4+reg
            int e = e0 + r;
            const float* p1 = P1 + (size_t)src[e] * HF;
            const float* p2 = P2 + (size_t)dst[e] * HF;
            float p = 0.f;
            #pragma unroll
            for (int ct = 0; ct < 4; ct++) {
                int c = w * 64 + ct * 16 + (l & 15);
                float v = acc[rt][ct][i] + p1[c] + p2[c] + b1v[ct];
                p += fmaxf(v, 0.f) * w2v[ct];
            }
            #pragma unroll
            for (int o = 8; o > 0; o >>= 1) p += __shfl_down(p, o, 16);
            if ((l & 15) == 0) part[r][w] = p;
        }
    }
    __syncthreads();
    if (tid < 64)
        out[e0 + tid] = part[tid][0] + part[tid][1] + part[tid][2] + part[tid][3] + b2[0];
}

// ---------------------------------------------------------------------------
// CSR build
// ---------------------------------------------------------------------------
__global__ void hist_kernel(const int* __restrict__ dst, int* __restrict__ deg, int E)
{
    int e = blockIdx.x * blockDim.x + threadIdx.x;
    if (e < E) atomicAdd(&deg[dst[e]], 1);
}

__global__ __launch_bounds__(1024) void scan_kernel(
    const int* __restrict__ deg, int* __restrict__ off, int* __restrict__ cur, int n)
{
    __shared__ int sums[1024];
    const int tid = threadIdx.x;
    const int chunk = (n + 1023) / 1024;
    const int start = tid * chunk;
    const int end = (start + chunk < n) ? (start + chunk) : n;
    int s = 0;
    for (int i = start; i < end; i++) s += deg[i];
    sums[tid] = s;
    __syncthreads();
    for (int d = 1; d < 1024; d <<= 1) {
        int t = 0;
        if (tid >= d) t = sums[tid - d];
        __syncthreads();
        if (tid >= d) sums[tid] += t;
        __syncthreads();
    }
    int run = (tid > 0) ? sums[tid - 1] : 0;
    for (int i = start; i < end; i++) {
        off[i] = run;
        cur[i] = run;
        run += deg[i];
    }
    if (tid == 1023) off[n] = sums[1023];
}

__global__ void fill_kernel(const int* __restrict__ dst, int* __restrict__ cur,
                            int* __restrict__ el, int E)
{
    int e = blockIdx.x * blockDim.x + threadIdx.x;
    if (e < E) {
        int p = atomicAdd(&cur[dst[e]], 1);
        el[p] = e;
    }
}

// ---------------------------------------------------------------------------
// Wave-per-node: edge softmax + weighted aggregation + GIN update, fused.
// ---------------------------------------------------------------------------
__global__ __launch_bounds__(256) void node_agg_update_kernel(
    const float* __restrict__ a, const int* __restrict__ off,
    const int* __restrict__ el, const int* __restrict__ src,
    const float* __restrict__ h, const float* __restrict__ gh,
    const float* __restrict__ eps, float* __restrict__ hn, int N)
{
    const int node = blockIdx.x * 4 + (threadIdx.x >> 6);
    const int lane = threadIdx.x & 63;
    if (node >= N) return;
    const int beg = off[node];
    const int deg = off[node + 1] - beg;
    const int c4 = lane << 2;

    float4 acc = make_float4(0.f, 0.f, 0.f, 0.f);
    if (deg > 0) {
        float mx = -INFINITY;
        for (int i = lane; i < deg; i += 64) mx = fmaxf(mx, a[el[beg + i]]);
        #pragma unroll
        for (int o = 32; o > 0; o >>= 1) mx = fmaxf(mx, __shfl_xor(mx, o, 64));
        float sm = 0.f;
        for (int i = lane; i < deg; i += 64) sm += expf(a[el[beg + i]] - mx);
        #pragma unroll
        for (int o = 32; o > 0; o >>= 1) sm += __shfl_xor(sm, o, 64);
        const float inv = 1.f / sm;
        for (int i = 0; i < deg; i++) {
            const int e = el[beg + i];
            const float at = expf(a[e] - mx) * inv;
            const float4 hs = *(const float4*)(h + (size_t)src[e] * HF + c4);
            const float4 ge = *(const float4*)(gh + (size_t)e * HF + c4);
            acc.x += at * hs.x * ge.x;
            acc.y += at * hs.y * ge.y;
            acc.z += at * hs.z * ge.z;
            acc.w += at * hs.w * ge.w;
        }
    }
    const float s = 1.f + eps[node];
    const float4 hp = *(const float4*)(h + (size_t)node * HF + c4);
    float4 o;
    o.x = s * acc.x + hp.x;
    o.y = s * acc.y + hp.y;
    o.z = s * acc.z + hp.z;
    o.w = s * acc.w + hp.w;
    *(float4*)(hn + (size_t)node * HF + c4) = o;
}

// ---------------------------------------------------------------------------
extern "C" void kernel_launch(void* const* d_in, const int* in_sizes, int n_in,
                              void* d_out, int out_size, void* d_ws, size_t ws_size,
                              hipStream_t stream)
{
    const float* node_feats = (const float*)d_in[0];
    const float* gh     = (const float*)d_in[1];
    const int*   src    = (const int*)d_in[2];
    const int*   dst    = (const int*)d_in[3];
    const float* Wn_w   = (const float*)d_in[4];
    const float* Wn_b   = (const float*)d_in[5];
    const float* eps_w1 = (const float*)d_in[6];
    const float* eps_b1 = (const float*)d_in[7];
    const float* eps_w2 = (const float*)d_in[8];
    const float* eps_b2 = (const float*)d_in[9];
    const float* a_w1   = (const float*)d_in[10];
    const float* a_b1   = (const float*)d_in[11];
    const float* a_w2   = (const float*)d_in[12];
    const float* a_b2   = (const float*)d_in[13];
    float* out = (float*)d_out;

    const int N = in_sizes[0] / D_INF;
    const int E = in_sizes[2];

    // workspace carve
    char* ws = (char*)d_ws;
    size_t off = 0;
    auto carve = [&](size_t bytes) -> void* {
        void* p = ws + off;
        off = (off + bytes + 255) & ~(size_t)255;
        return p;
    };
    float* P1  = (float*)carve((size_t)N * HF * 4);
    float* P2  = (float*)carve((size_t)N * HF * 4);
    float* ASC = (float*)carve((size_t)E * 4);
    float* EPS = (float*)carve((size_t)N * 4);
    int*   DEG = (int*)carve((size_t)N * 4);
    int*   OFFS= (int*)carve((size_t)(N + 1) * 4);
    int*   CUR = (int*)carve((size_t)N * 4);
    int*   EL  = (int*)carve((size_t)E * 4);
    short* WhiT= (short*)carve((size_t)LF * HF * HF * 2);
    short* WloT= (short*)carve((size_t)LF * HF * HF * 2);
    const bool use_mfma = (off <= ws_size) && (E % 64 == 0);

    // CSR build (rebuilt every call; nothing persists across launches)
    hipMemsetAsync(DEG, 0, (size_t)N * 4, stream);
    hist_kernel<<<(E + 255) / 256, 256, 0, stream>>>(dst, DEG, E);
    scan_kernel<<<1, 1024, 0, stream>>>(DEG, OFFS, CUR, N);
    fill_kernel<<<(E + 255) / 256, 256, 0, stream>>>(dst, CUR, EL, E);

    if (use_mfma)
        conv_w1cT_kernel<<<(LF * HF * HF + 255) / 256, 256, 0, stream>>>(a_w1, WhiT, WloT);

    dim3 gg((N + 63) / 64, HF / 64);

    // input projection -> outs[0]
    gemm_f32<<<gg, 256, 0, stream>>>(node_feats, Wn_w, Wn_b, out, N, D_INF, HF);

    const int egrid = (E + 63) / 64;
    const int ngrid = (N + 63) / 64;

    for (int l = 0; l < LF; l++) {
        const float* h  = out + (size_t)l * N * HF;
        float*       hn = out + (size_t)(l + 1) * N * HF;
        const float* W1  = a_w1 + (size_t)l * 3 * HF * HF;
        const float* W1a = W1;
        const float* W1b = W1 + (size_t)HF * HF;
        const float* W1c = W1 + (size_t)2 * HF * HF;
        const float* b1  = a_b1 + (size_t)l * HF;
        const float* w2  = a_w2 + (size_t)l * HF;
        const float* b2  = a_b2 + l;

        // node-level projections of the split attention W1
        gemm_f32<<<gg, 256, 0, stream>>>(h, W1a, nullptr, P1, N, HF, HF);
        gemm_f32<<<gg, 256, 0, stream>>>(h, W1b, nullptr, P2, N, HF, HF);

        // per-edge attention logits (fused GEMM + gather + relu + dot)
        if (use_mfma) {
            edge_mfma_kernel<<<E / 64, 256, 0, stream>>>(
                gh, WhiT + (size_t)l * HF * HF, WloT + (size_t)l * HF * HF,
                b1, w2, b2, P1, P2, src, dst, ASC);
        } else {
            mlp_score_kernel<<<egrid, 256, 0, stream>>>(
                gh, W1c, b1, w2, b2, P1, P2, src, dst, ASC, E, HF);
        }

        // per-node epsilon (fused GEMM + relu + dot)
        mlp_score_kernel<<<ngrid, 256, 0, stream>>>(
            h, eps_w1 + (size_t)l * HF * HF, eps_b1 + (size_t)l * HF,
            eps_w2 + (size_t)l * HF, eps_b2 + l,
            nullptr, nullptr, nullptr, nullptr, EPS, N, HF);

        // softmax + aggregate + GIN update, fused
        node_agg_update_kernel<<<(N + 3) / 4, 256, 0, stream>>>(
            ASC, OFFS, EL, src, h, gh, EPS, hn, N);
    }
}

// Round 5
// 1018.241 us; speedup vs baseline: 1.1144x; 1.1144x over previous
//
#include <hip/hip_runtime.h>
#include <hip/hip_bf16.h>
#include <math.h>

#define D_INF 128
#define HF    256
#define LF    3

typedef float f32x4 __attribute__((ext_vector_type(4)));
typedef short bf16x8 __attribute__((ext_vector_type(8)));

// round-to-nearest-even f32 -> bf16 (bit pattern) + rounded value as f32
__device__ __forceinline__ void rne_bf16(float x, short& h, float& hf) {
    uint32_t u = __float_as_uint(x);
    uint32_t r = u + 0x7FFFu + ((u >> 16) & 1u);
    r &= 0xFFFF0000u;
    h = (short)(r >> 16);
    hf = __uint_as_float(r);
}

// async global->LDS, 16B per lane: HW writes lane i at ldsbase + i*16
__device__ __forceinline__ void glds16(const void* g, void* l) {
    __builtin_amdgcn_global_load_lds(
        (const __attribute__((address_space(1))) void*)g,
        (__attribute__((address_space(3))) void*)l, 16, 0, 0);
}

// ===========================================================================
// f32 GEMM (fallback path)
// ===========================================================================
__global__ __launch_bounds__(256) void gemm_f32(
    const float* __restrict__ A, const float* __restrict__ B,
    const float* __restrict__ bias, float* __restrict__ C,
    int M, int K, int N)
{
    __shared__ __align__(16) float As[16][68];
    __shared__ __align__(16) float Bs[16][68];
    const int tid = threadIdx.x;
    const int tx = tid & 15, ty = tid >> 4;
    const int row0 = blockIdx.x * 64;
    const int col0 = blockIdx.y * 64;
    float acc[4][4] = {};

    for (int k0 = 0; k0 < K; k0 += 16) {
        {
            int m = tid >> 2, kk4 = (tid & 3) << 2;
            int gr = row0 + m;
            float4 v = make_float4(0.f, 0.f, 0.f, 0.f);
            if (gr < M) v = *(const float4*)(A + (size_t)gr * K + k0 + kk4);
            As[kk4 + 0][m] = v.x;
            As[kk4 + 1][m] = v.y;
            As[kk4 + 2][m] = v.z;
            As[kk4 + 3][m] = v.w;
        }
        {
            int kk = tid >> 4, n4 = (tid & 15) << 2;
            float4 v = *(const float4*)(B + (size_t)(k0 + kk) * N + col0 + n4);
            *(float4*)&Bs[kk][n4] = v;
        }
        __syncthreads();
        #pragma unroll
        for (int kk = 0; kk < 16; kk++) {
            float a4[4], b4[4];
            *(float4*)a4 = *(const float4*)&As[kk][ty << 2];
            *(float4*)b4 = *(const float4*)&Bs[kk][tx << 2];
            #pragma unroll
            for (int i = 0; i < 4; i++)
                #pragma unroll
                for (int j = 0; j < 4; j++)
                    acc[i][j] += a4[i] * b4[j];
        }
        __syncthreads();
    }

    int c = col0 + (tx << 2);
    #pragma unroll
    for (int i = 0; i < 4; i++) {
        int r = row0 + (ty << 2) + i;
        if (r >= M) continue;
        float4 o;
        o.x = acc[i][0]; o.y = acc[i][1]; o.z = acc[i][2]; o.w = acc[i][3];
        if (bias) {
            o.x += bias[c + 0]; o.y += bias[c + 1];
            o.z += bias[c + 2]; o.w += bias[c + 3];
        }
        *(float4*)(C + (size_t)r * N + c) = o;
    }
}

// ===========================================================================
// f32 fused MLP-to-scalar (fallback)
// ===========================================================================
__global__ __launch_bounds__(256) void mlp_score_kernel(
    const float* __restrict__ A, const float* __restrict__ B,
    const float* __restrict__ b1, const float* __restrict__ w2,
    const float* __restrict__ b2,
    const float* __restrict__ P1, const float* __restrict__ P2,
    const int* __restrict__ src, const int* __restrict__ dst,
    float* __restrict__ out, int M, int K)
{
    __shared__ __align__(16) float As[16][68];
    __shared__ __align__(16) float Bs[16][260];
    const int tid = threadIdx.x;
    const int tx = tid & 15, ty = tid >> 4;
    const int row0 = blockIdx.x * 64;
    float acc[4][16] = {};

    for (int k0 = 0; k0 < K; k0 += 16) {
        {
            int m = tid >> 2, kk4 = (tid & 3) << 2;
            int gr = row0 + m;
            float4 v = make_float4(0.f, 0.f, 0.f, 0.f);
            if (gr < M) v = *(const float4*)(A + (size_t)gr * K + k0 + kk4);
            As[kk4 + 0][m] = v.x;
            As[kk4 + 1][m] = v.y;
            As[kk4 + 2][m] = v.z;
            As[kk4 + 3][m] = v.w;
        }
        {
            int kk = ty;
            int cb = tx << 4;
            const float* bp = B + (size_t)(k0 + kk) * HF + cb;
            *(float4*)&Bs[kk][cb +  0] = *(const float4*)(bp +  0);
            *(float4*)&Bs[kk][cb +  4] = *(const float4*)(bp +  4);
            *(float4*)&Bs[kk][cb +  8] = *(const float4*)(bp +  8);
            *(float4*)&Bs[kk][cb + 12] = *(const float4*)(bp + 12);
        }
        __syncthreads();
        #pragma unroll
        for (int kk = 0; kk < 16; kk++) {
            float a4[4];
            *(float4*)a4 = *(const float4*)&As[kk][ty << 2];
            float b16[16];
            #pragma unroll
            for (int cb = 0; cb < 4; cb++)
                *(float4*)&b16[cb * 4] = *(const float4*)&Bs[kk][cb * 64 + (tx << 2)];
            #pragma unroll
            for (int i = 0; i < 4; i++)
                #pragma unroll
                for (int j = 0; j < 16; j++)
                    acc[i][j] += a4[i] * b16[j];
        }
        __syncthreads();
    }

    float b1v[16], w2v[16];
    #pragma unroll
    for (int cb = 0; cb < 4; cb++) {
        *(float4*)&b1v[cb * 4] = *(const float4*)(b1 + cb * 64 + (tx << 2));
        *(float4*)&w2v[cb * 4] = *(const float4*)(w2 + cb * 64 + (tx << 2));
    }
    const float bias2 = b2[0];

    #pragma unroll
    for (int i = 0; i < 4; i++) {
        int r = row0 + (ty << 2) + i;
        if (r < M) {
            float p = 0.f;
            if (P1) {
                const float* p1 = P1 + (size_t)src[r] * HF;
                const float* p2 = P2 + (size_t)dst[r] * HF;
                #pragma unroll
                for (int cb = 0; cb < 4; cb++) {
                    float g1[4], g2[4];
                    *(float4*)g1 = *(const float4*)(p1 + cb * 64 + (tx << 2));
                    *(float4*)g2 = *(const float4*)(p2 + cb * 64 + (tx << 2));
                    #pragma unroll
                    for (int j = 0; j < 4; j++) {
                        float v = acc[i][cb * 4 + j] + g1[j] + g2[j] + b1v[cb * 4 + j];
                        p += fmaxf(v, 0.f) * w2v[cb * 4 + j];
                    }
                }
            } else {
                #pragma unroll
                for (int j = 0; j < 16; j++) {
                    float v = acc[i][j] + b1v[j];
                    p += fmaxf(v, 0.f) * w2v[j];
                }
            }
            #pragma unroll
            for (int o = 8; o > 0; o >>= 1) p += __shfl_down(p, o, 16);
            if (tx == 0) out[r] = p + bias2;
        }
    }
}

// ===========================================================================
// Round-3 validated fallback: swizzled weight conv + register-staged edge MFMA
// ===========================================================================
__global__ void conv_w1cT_kernel(const float* __restrict__ a_w1,
                                 short* __restrict__ WhiT, short* __restrict__ WloT)
{
    int t = blockIdx.x * blockDim.x + threadIdx.x;
    if (t >= LF * HF * HF) return;
    int c  = t & 255;
    int k  = (t >> 8) & 255;
    int ly = t >> 16;
    float x = a_w1[((size_t)ly * 3 * HF + 2 * HF + k) * HF + c];
    short hh, ll; float hf, lf_;
    rne_bf16(x, hh, hf);
    rne_bf16(x - hf, ll, lf_);
    int ck = k >> 5;
    int j  = ((((k >> 3) & 3) ^ ((c >> 2) & 3)) << 3) + (k & 7);
    size_t d = (((size_t)ly * 8 + ck) * 256 + c) * 32 + j;
    WhiT[d] = hh;
    WloT[d] = ll;
}

__global__ __launch_bounds__(256) void edge_mfma_kernel(
    const float* __restrict__ gh,
    const short* __restrict__ WhiT, const short* __restrict__ WloT,
    const float* __restrict__ b1, const float* __restrict__ w2,
    const float* __restrict__ b2,
    const float* __restrict__ P1, const float* __restrict__ P2,
    const int* __restrict__ src, const int* __restrict__ dst,
    float* __restrict__ out)
{
    __shared__ __align__(16) short Ahi[64 * 32];
    __shared__ __align__(16) short Alo[64 * 32];
    __shared__ __align__(16) short Bhi[256 * 32];
    __shared__ __align__(16) short Blo[256 * 32];
    __shared__ float part[64][4];

    const int tid = threadIdx.x;
    const int w   = tid >> 6;
    const int l   = tid & 63;
    const int g   = l >> 4;
    const int e0  = blockIdx.x * 64;

    f32x4 acc[4][4];
    #pragma unroll
    for (int i = 0; i < 4; i++)
        #pragma unroll
        for (int j = 0; j < 4; j++)
            acc[i][j] = (f32x4){0.f, 0.f, 0.f, 0.f};

    for (int ck = 0; ck < 8; ck++) {
        const int k0 = ck * 32;
        {
            const short* sHi = WhiT + (size_t)ck * (256 * 32);
            const short* sLo = WloT + (size_t)ck * (256 * 32);
            #pragma unroll
            for (int p = 0; p < 4; p++) {
                int off8 = (p * 256 + tid) * 8;
                *(bf16x8*)&Bhi[off8] = *(const bf16x8*)&sHi[off8];
                *(bf16x8*)&Blo[off8] = *(const bf16x8*)&sLo[off8];
            }
        }
        {
            const int r = tid >> 2, p = tid & 3;
            const float* gp = gh + (size_t)(e0 + r) * HF + k0 + p * 8;
            float vf[8];
            *(float4*)&vf[0] = *(const float4*)gp;
            *(float4*)&vf[4] = *(const float4*)(gp + 4);
            bf16x8 hv, lv;
            #pragma unroll
            for (int j = 0; j < 8; j++) {
                short hh, ll; float hf, lf_;
                rne_bf16(vf[j], hh, hf);
                rne_bf16(vf[j] - hf, ll, lf_);
                hv[j] = hh;
                lv[j] = ll;
            }
            const int s = p ^ ((r >> 2) & 3);
            *(bf16x8*)&Ahi[(r * 4 + s) * 8] = hv;
            *(bf16x8*)&Alo[(r * 4 + s) * 8] = lv;
        }
        __syncthreads();

        bf16x8 ah[4], al[4];
        #pragma unroll
        for (int rt = 0; rt < 4; rt++) {
            int r = rt * 16 + (l & 15);
            int s = g ^ ((r >> 2) & 3);
            ah[rt] = *(const bf16x8*)&Ahi[(r * 4 + s) * 8];
            al[rt] = *(const bf16x8*)&Alo[(r * 4 + s) * 8];
        }
        #pragma unroll
        for (int ct = 0; ct < 4; ct++) {
            int c = w * 64 + ct * 16 + (l & 15);
            int s = g ^ ((c >> 2) & 3);
            bf16x8 bh = *(const bf16x8*)&Bhi[(c * 4 + s) * 8];
            bf16x8 bl = *(const bf16x8*)&Blo[(c * 4 + s) * 8];
            #pragma unroll
            for (int rt = 0; rt < 4; rt++) {
                acc[rt][ct] = __builtin_amdgcn_mfma_f32_16x16x32_bf16(ah[rt], bh, acc[rt][ct], 0, 0, 0);
                acc[rt][ct] = __builtin_amdgcn_mfma_f32_16x16x32_bf16(al[rt], bh, acc[rt][ct], 0, 0, 0);
                acc[rt][ct] = __builtin_amdgcn_mfma_f32_16x16x32_bf16(ah[rt], bl, acc[rt][ct], 0, 0, 0);
            }
        }
        __syncthreads();
    }

    float w2v[4], b1v[4];
    #pragma unroll
    for (int ct = 0; ct < 4; ct++) {
        int c = w * 64 + ct * 16 + (l & 15);
        w2v[ct] = w2[c];
        b1v[ct] = b1[c];
    }
    #pragma unroll
    for (int rt = 0; rt < 4; rt++) {
        #pragma unroll
        for (int i = 0; i < 4; i++) {
            int r = rt * 16 + g * 4 + i;
            int e = e0 + r;
            const float* p1 = P1 + (size_t)src[e] * HF;
            const float* p2 = P2 + (size_t)dst[e] * HF;
            float p = 0.f;
            #pragma unroll
            for (int ct = 0; ct < 4; ct++) {
                int c = w * 64 + ct * 16 + (l & 15);
                float v = acc[rt][ct][i] + p1[c] + p2[c] + b1v[ct];
                p += fmaxf(v, 0.f) * w2v[ct];
            }
            #pragma unroll
            for (int o = 8; o > 0; o >>= 1) p += __shfl_down(p, o, 16);
            if ((l & 15) == 0) part[r][w] = p;
        }
    }
    __syncthreads();
    if (tid < 64)
        out[e0 + tid] = part[tid][0] + part[tid][1] + part[tid][2] + part[tid][3] + b2[0];
}

// ===========================================================================
// FAST PATH: blocked-chunk-major split planes + glds double-buffered MFMA
// Blocked layout (shorts): plane[(row/64)*(K*64) + (k/32)*2048 + (row%64)*32 + k%32]
// ===========================================================================

// split f32 -> (hi,lo) bf16 planes in blocked layout. kgshift: log2(K/8).
__global__ void split_blocked_kernel(const float* __restrict__ x,
                                     short* __restrict__ hi, short* __restrict__ lo,
                                     long M, int K, int kgshift)
{
    const long n8 = M << kgshift;
    const int kgmask = (1 << kgshift) - 1;
    for (long i = (long)blockIdx.x * blockDim.x + threadIdx.x; i < n8;
         i += (long)gridDim.x * blockDim.x) {
        long e = i >> kgshift;
        int k0 = (int)(i & kgmask) << 3;
        const float* p = x + e * K + k0;
        float v[8];
        *(float4*)&v[0] = *(const float4*)p;
        *(float4*)&v[4] = *(const float4*)(p + 4);
        bf16x8 h8, l8;
        #pragma unroll
        for (int j = 0; j < 8; j++) {
            short hh, ll; float hf, lf_;
            rne_bf16(v[j], hh, hf);
            rne_bf16(v[j] - hf, ll, lf_);
            h8[j] = hh; l8[j] = ll;
        }
        size_t d = (size_t)(e >> 6) * ((size_t)K << 6) + (size_t)(k0 >> 5) * 2048
                 + (size_t)(e & 63) * 32 + (k0 & 31);
        *(bf16x8*)&hi[d] = h8;
        *(bf16x8*)&lo[d] = l8;
    }
}

// a_w1 -> per (layer,block) chunk images: base (l*3+b)*65536 + ck*8192 + c*32 + k%32
__global__ void conv_aw1_kernel(const float* __restrict__ a_w1,
                                short* __restrict__ Whi, short* __restrict__ Wlo)
{
    int t = blockIdx.x * blockDim.x + threadIdx.x;
    if (t >= LF * 3 * HF * HF) return;
    int c = t & 255;
    int k = (t >> 8) & 255;
    int b = (t >> 16) % 3;
    int l = t / (3 * HF * HF);
    float x = a_w1[((size_t)l * 3 * HF + b * HF + k) * HF + c];
    short hh, ll; float hf, lf_;
    rne_bf16(x, hh, hf);
    rne_bf16(x - hf, ll, lf_);
    size_t d = (size_t)(l * 3 + b) * 65536 + (size_t)(k >> 5) * 8192 + c * 32 + (k & 31);
    Whi[d] = hh;
    Wlo[d] = ll;
}

// eps_w1 -> chunk images at l*65536
__global__ void conv_epsw1_kernel(const float* __restrict__ eps_w1,
                                  short* __restrict__ Ehi, short* __restrict__ Elo)
{
    int t = blockIdx.x * blockDim.x + threadIdx.x;
    if (t >= LF * HF * HF) return;
    int c = t & 255;
    int k = (t >> 8) & 255;
    int l = t >> 16;
    float x = eps_w1[((size_t)l * HF + k) * HF + c];
    short hh, ll; float hf, lf_;
    rne_bf16(x, hh, hf);
    rne_bf16(x - hf, ll, lf_);
    size_t d = (size_t)l * 65536 + (size_t)(k >> 5) * 8192 + c * 32 + (k & 31);
    Ehi[d] = hh;
    Elo[d] = ll;
}

// W_n (128x256) -> 4 chunk images
__global__ void conv_wn_kernel(const float* __restrict__ Wn,
                               short* __restrict__ Whi, short* __restrict__ Wlo)
{
    int t = blockIdx.x * blockDim.x + threadIdx.x;
    if (t >= D_INF * HF) return;
    int c = t & 255;
    int k = t >> 8;           // 0..127
    float x = Wn[(size_t)k * HF + c];
    short hh, ll; float hf, lf_;
    rne_bf16(x, hh, hf);
    rne_bf16(x - hf, ll, lf_);
    size_t d = (size_t)(k >> 5) * 8192 + c * 32 + (k & 31);
    Whi[d] = hh;
    Wlo[d] = ll;
}

#define LDSB 40960  // per buffer: Ahi 4K | Alo 4K | Bhi 16K | Blo 16K

// stage one chunk: A chunk base (2048 shorts, blocked) + B chunk base (8192 shorts)
__device__ __forceinline__ void stage_ab(
    char* sb,
    const short* __restrict__ Ah, const short* __restrict__ Al,
    const short* __restrict__ Bh, const short* __restrict__ Bl,
    int w, int l)
{
    const int a_off = w * 512 + l * 8;     // shorts
    glds16(Ah + a_off, sb + w * 1024);
    glds16(Al + a_off, sb + 4096 + w * 1024);
    const int loff = l * 8;
    #pragma unroll
    for (int i = 0; i < 4; i++) {
        int q = (w << 2) + i;
        glds16(Bh + q * 512 + loff, sb + 8192  + q * 1024);
        glds16(Bl + q * 512 + loff, sb + 24576 + q * 1024);
    }
}

// MFMA compute for one chunk (LDS A:[64][32], B:[256][32])
__device__ __forceinline__ void compute_chunk(
    const char* cb, int w, int lr, int g, f32x4 acc[4][4])
{
    const short* Ah = (const short*)(cb);
    const short* Al = (const short*)(cb + 4096);
    const short* Bh = (const short*)(cb + 8192);
    const short* Bl = (const short*)(cb + 24576);
    bf16x8 ah[4], al[4];
    #pragma unroll
    for (int rt = 0; rt < 4; rt++) {
        int r = rt * 16 + lr;
        ah[rt] = *(const bf16x8*)&Ah[r * 32 + g * 8];
        al[rt] = *(const bf16x8*)&Al[r * 32 + g * 8];
    }
    #pragma unroll
    for (int ct = 0; ct < 4; ct++) {
        int c = w * 64 + ct * 16 + lr;
        bf16x8 bh = *(const bf16x8*)&Bh[c * 32 + g * 8];
        bf16x8 bl = *(const bf16x8*)&Bl[c * 32 + g * 8];
        #pragma unroll
        for (int rt = 0; rt < 4; rt++) {
            acc[rt][ct] = __builtin_amdgcn_mfma_f32_16x16x32_bf16(ah[rt], bh, acc[rt][ct], 0, 0, 0);
            acc[rt][ct] = __builtin_amdgcn_mfma_f32_16x16x32_bf16(al[rt], bh, acc[rt][ct], 0, 0, 0);
            acc[rt][ct] = __builtin_amdgcn_mfma_f32_16x16x32_bf16(ah[rt], bl, acc[rt][ct], 0, 0, 0);
        }
    }
}

// ---------------------------------------------------------------------------
// Edge scores: a[e] = relu(gh[e]@W1c + P1[src] + P2[dst] + b1) . w2 + b2
// ---------------------------------------------------------------------------
__global__ __launch_bounds__(256) void edge_mfma2_kernel(
    const short* __restrict__ ghhi, const short* __restrict__ ghlo,
    const short* __restrict__ Wc_hi, const short* __restrict__ Wc_lo,
    const float* __restrict__ b1, const float* __restrict__ w2,
    const float* __restrict__ b2,
    const float* __restrict__ P1, const float* __restrict__ P2,
    const int* __restrict__ src, const int* __restrict__ dst,
    float* __restrict__ out)
{
    __shared__ __align__(16) char smem[2 * LDSB];
    const int tid = threadIdx.x;
    const int w = tid >> 6, l = tid & 63;
    const int lr = l & 15, g = l >> 4;
    const long row0 = (long)blockIdx.x * 64;
    const size_t ablk = (size_t)blockIdx.x << 14;   // 64*256 shorts per block

    f32x4 acc[4][4];
    #pragma unroll
    for (int i = 0; i < 4; i++)
        #pragma unroll
        for (int j = 0; j < 4; j++)
            acc[i][j] = (f32x4){0.f, 0.f, 0.f, 0.f};

    stage_ab(smem, ghhi + ablk, ghlo + ablk, Wc_hi, Wc_lo, w, l);
    __syncthreads();
    for (int ck = 0; ck < 8; ck++) {
        if (ck < 7)
            stage_ab(smem + ((ck + 1) & 1) * LDSB,
                     ghhi + ablk + (ck + 1) * 2048, ghlo + ablk + (ck + 1) * 2048,
                     Wc_hi + (ck + 1) * 8192, Wc_lo + (ck + 1) * 8192, w, l);
        compute_chunk(smem + (ck & 1) * LDSB, w, lr, g, acc);
        __syncthreads();   // vmcnt(0)+barrier: prefetched buffer ready
    }

    // epilogue: gather + relu + dot(w2) + cross-wave reduce (part aliases smem)
    float* part = (float*)smem;  // [64][4]
    float w2v[4], b1v[4];
    #pragma unroll
    for (int ct = 0; ct < 4; ct++) {
        int c = w * 64 + ct * 16 + lr;
        w2v[ct] = w2[c];
        b1v[ct] = b1[c];
    }
    #pragma unroll
    for (int rt = 0; rt < 4; rt++) {
        #pragma unroll
        for (int i = 0; i < 4; i++) {
            int r = rt * 16 + g * 4 + i;
            long e = row0 + r;
            const float* p1 = P1 + (size_t)src[e] * HF;
            const float* p2 = P2 + (size_t)dst[e] * HF;
            float p = 0.f;
            #pragma unroll
            for (int ct = 0; ct < 4; ct++) {
                int c = w * 64 + ct * 16 + lr;
                float v = acc[rt][ct][i] + p1[c] + p2[c] + b1v[ct];
                p += fmaxf(v, 0.f) * w2v[ct];
            }
            #pragma unroll
            for (int o = 8; o > 0; o >>= 1) p += __shfl_down(p, o, 16);
            if (lr == 0) part[r * 4 + w] = p;
        }
    }
    __syncthreads();
    if (tid < 64)
        out[row0 + tid] = part[tid * 4 + 0] + part[tid * 4 + 1] +
                          part[tid * 4 + 2] + part[tid * 4 + 3] + b2[0];
}

// ---------------------------------------------------------------------------
// Node GEMMs: grid (nblk, 3). y=0: P1=h@W1a; y=1: P2=h@W1b; y=2: EPS mlp.
// ---------------------------------------------------------------------------
__global__ __launch_bounds__(256) void node_mfma_kernel(
    const short* __restrict__ hhi, const short* __restrict__ hlo,
    const short* __restrict__ Wa_hi, const short* __restrict__ Wa_lo,
    const short* __restrict__ Ee_hi, const short* __restrict__ Ee_lo,
    const float* __restrict__ eb1, const float* __restrict__ ew2,
    const float* __restrict__ eb2,
    float* __restrict__ P1o, float* __restrict__ P2o,
    float* __restrict__ EPSo, int N)
{
    __shared__ __align__(16) char smem[2 * LDSB];
    const int tid = threadIdx.x;
    const int w = tid >> 6, l = tid & 63;
    const int lr = l & 15, g = l >> 4;
    const int y = blockIdx.y;
    const long row0 = (long)blockIdx.x * 64;
    const size_t ablk = (size_t)blockIdx.x << 14;

    const short* Bhi_g;
    const short* Blo_g;
    if (y == 0)      { Bhi_g = Wa_hi;         Blo_g = Wa_lo; }
    else if (y == 1) { Bhi_g = Wa_hi + 65536; Blo_g = Wa_lo + 65536; }
    else             { Bhi_g = Ee_hi;         Blo_g = Ee_lo; }

    f32x4 acc[4][4];
    #pragma unroll
    for (int i = 0; i < 4; i++)
        #pragma unroll
        for (int j = 0; j < 4; j++)
            acc[i][j] = (f32x4){0.f, 0.f, 0.f, 0.f};

    stage_ab(smem, hhi + ablk, hlo + ablk, Bhi_g, Blo_g, w, l);
    __syncthreads();
    for (int ck = 0; ck < 8; ck++) {
        if (ck < 7)
            stage_ab(smem + ((ck + 1) & 1) * LDSB,
                     hhi + ablk + (ck + 1) * 2048, hlo + ablk + (ck + 1) * 2048,
                     Bhi_g + (ck + 1) * 8192, Blo_g + (ck + 1) * 8192, w, l);
        compute_chunk(smem + (ck & 1) * LDSB, w, lr, g, acc);
        __syncthreads();
    }

    if (y < 2) {
        float* P = (y == 0) ? P1o : P2o;
        #pragma unroll
        for (int rt = 0; rt < 4; rt++) {
            #pragma unroll
            for (int i = 0; i < 4; i++) {
                long grow = row0 + rt * 16 + g * 4 + i;
                if (grow < N) {
                    #pragma unroll
                    for (int ct = 0; ct < 4; ct++) {
                        int c = w * 64 + ct * 16 + lr;
                        P[grow * HF + c] = acc[rt][ct][i];
                    }
                }
            }
        }
    } else {
        float* part = (float*)smem;  // [64][4]
        float w2v[4], b1v[4];
        #pragma unroll
        for (int ct = 0; ct < 4; ct++) {
            int c = w * 64 + ct * 16 + lr;
            w2v[ct] = ew2[c];
            b1v[ct] = eb1[c];
        }
        #pragma unroll
        for (int rt = 0; rt < 4; rt++) {
            #pragma unroll
            for (int i = 0; i < 4; i++) {
                int r = rt * 16 + g * 4 + i;
                float p = 0.f;
                #pragma unroll
                for (int ct = 0; ct < 4; ct++) {
                    float v = acc[rt][ct][i] + b1v[ct];
                    p += fmaxf(v, 0.f) * w2v[ct];
                }
                #pragma unroll
                for (int o = 8; o > 0; o >>= 1) p += __shfl_down(p, o, 16);
                if (lr == 0) part[r * 4 + w] = p;
            }
        }
        __syncthreads();
        if (tid < 64 && row0 + tid < N)
            EPSo[row0 + tid] = part[tid * 4 + 0] + part[tid * 4 + 1] +
                               part[tid * 4 + 2] + part[tid * 4 + 3] + eb2[0];
    }
}

// ---------------------------------------------------------------------------
// Input projection: out0 = node_feats @ W_n + b   (K = 128, 4 chunks)
// ---------------------------------------------------------------------------
__global__ __launch_bounds__(256) void proj_mfma_kernel(
    const short* __restrict__ nfhi, const short* __restrict__ nflo,
    const short* __restrict__ Wnhi, const short* __restrict__ Wnlo,
    const float* __restrict__ bias, float* __restrict__ out, int N)
{
    __shared__ __align__(16) char smem[2 * LDSB];
    const int tid = threadIdx.x;
    const int w = tid >> 6, l = tid & 63;
    const int lr = l & 15, g = l >> 4;
    const long row0 = (long)blockIdx.x * 64;
    const size_t ablk = (size_t)blockIdx.x << 13;   // 64*128 shorts per block

    f32x4 acc[4][4];
    #pragma unroll
    for (int i = 0; i < 4; i++)
        #pragma unroll
        for (int j = 0; j < 4; j++)
            acc[i][j] = (f32x4){0.f, 0.f, 0.f, 0.f};

    stage_ab(smem, nfhi + ablk, nflo + ablk, Wnhi, Wnlo, w, l);
    __syncthreads();
    for (int ck = 0; ck < 4; ck++) {
        if (ck < 3)
            stage_ab(smem + ((ck + 1) & 1) * LDSB,
                     nfhi + ablk + (ck + 1) * 2048, nflo + ablk + (ck + 1) * 2048,
                     Wnhi + (ck + 1) * 8192, Wnlo + (ck + 1) * 8192, w, l);
        compute_chunk(smem + (ck & 1) * LDSB, w, lr, g, acc);
        __syncthreads();
    }

    #pragma unroll
    for (int rt = 0; rt < 4; rt++) {
        #pragma unroll
        for (int i = 0; i < 4; i++) {
            long grow = row0 + rt * 16 + g * 4 + i;
            if (grow < N) {
                #pragma unroll
                for (int ct = 0; ct < 4; ct++) {
                    int c = w * 64 + ct * 16 + lr;
                    out[grow * HF + c] = acc[rt][ct][i] + bias[c];
                }
            }
        }
    }
}

// ===========================================================================
// CSR build
// ===========================================================================
__global__ void hist_kernel(const int* __restrict__ dst, int* __restrict__ deg, int E)
{
    int e = blockIdx.x * blockDim.x + threadIdx.x;
    if (e < E) atomicAdd(&deg[dst[e]], 1);
}

__global__ __launch_bounds__(1024) void scan_kernel(
    const int* __restrict__ deg, int* __restrict__ off, int* __restrict__ cur, int n)
{
    __shared__ int sums[1024];
    const int tid = threadIdx.x;
    const int chunk = (n + 1023) / 1024;
    const int start = tid * chunk;
    const int end = (start + chunk < n) ? (start + chunk) : n;
    int s = 0;
    for (int i = start; i < end; i++) s += deg[i];
    sums[tid] = s;
    __syncthreads();
    for (int d = 1; d < 1024; d <<= 1) {
        int t = 0;
        if (tid >= d) t = sums[tid - d];
        __syncthreads();
        if (tid >= d) sums[tid] += t;
        __syncthreads();
    }
    int run = (tid > 0) ? sums[tid - 1] : 0;
    for (int i = start; i < end; i++) {
        off[i] = run;
        cur[i] = run;
        run += deg[i];
    }
    if (tid == 1023) off[n] = sums[1023];
}

__global__ void fill_kernel(const int* __restrict__ dst, int* __restrict__ cur,
                            int* __restrict__ el, int E)
{
    int e = blockIdx.x * blockDim.x + threadIdx.x;
    if (e < E) {
        int p = atomicAdd(&cur[dst[e]], 1);
        el[p] = e;
    }
}

// ===========================================================================
// softmax + aggregate + GIN update (fused)
// ===========================================================================
__global__ __launch_bounds__(256) void node_agg_update_kernel(
    const float* __restrict__ a, const int* __restrict__ off,
    const int* __restrict__ el, const int* __restrict__ src,
    const float* __restrict__ h, const float* __restrict__ gh,
    const float* __restrict__ eps, float* __restrict__ hn, int N)
{
    const int node = blockIdx.x * 4 + (threadIdx.x >> 6);
    const int lane = threadIdx.x & 63;
    if (node >= N) return;
    const int beg = off[node];
    const int deg = off[node + 1] - beg;
    const int c4 = lane << 2;

    float4 acc = make_float4(0.f, 0.f, 0.f, 0.f);
    if (deg > 0) {
        float mx = -INFINITY;
        for (int i = lane; i < deg; i += 64) mx = fmaxf(mx, a[el[beg + i]]);
        #pragma unroll
        for (int o = 32; o > 0; o >>= 1) mx = fmaxf(mx, __shfl_xor(mx, o, 64));
        float sm = 0.f;
        for (int i = lane; i < deg; i += 64) sm += expf(a[el[beg + i]] - mx);
        #pragma unroll
        for (int o = 32; o > 0; o >>= 1) sm += __shfl_xor(sm, o, 64);
        const float inv = 1.f / sm;
        for (int i = 0; i < deg; i++) {
            const int e = el[beg + i];
            const float at = expf(a[e] - mx) * inv;
            const float4 hs = *(const float4*)(h + (size_t)src[e] * HF + c4);
            const float4 ge = *(const float4*)(gh + (size_t)e * HF + c4);
            acc.x += at * hs.x * ge.x;
            acc.y += at * hs.y * ge.y;
            acc.z += at * hs.z * ge.z;
            acc.w += at * hs.w * ge.w;
        }
    }
    const float s = 1.f + eps[node];
    const float4 hp = *(const float4*)(h + (size_t)node * HF + c4);
    float4 o;
    o.x = s * acc.x + hp.x;
    o.y = s * acc.y + hp.y;
    o.z = s * acc.z + hp.z;
    o.w = s * acc.w + hp.w;
    *(float4*)(hn + (size_t)node * HF + c4) = o;
}

// ===========================================================================
extern "C" void kernel_launch(void* const* d_in, const int* in_sizes, int n_in,
                              void* d_out, int out_size, void* d_ws, size_t ws_size,
                              hipStream_t stream)
{
    const float* node_feats = (const float*)d_in[0];
    const float* gh     = (const float*)d_in[1];
    const int*   src    = (const int*)d_in[2];
    const int*   dst    = (const int*)d_in[3];
    const float* Wn_w   = (const float*)d_in[4];
    const float* Wn_b   = (const float*)d_in[5];
    const float* eps_w1 = (const float*)d_in[6];
    const float* eps_b1 = (const float*)d_in[7];
    const float* eps_w2 = (const float*)d_in[8];
    const float* eps_b2 = (const float*)d_in[9];
    const float* a_w1   = (const float*)d_in[10];
    const float* a_b1   = (const float*)d_in[11];
    const float* a_w2   = (const float*)d_in[12];
    const float* a_b2   = (const float*)d_in[13];
    float* out = (float*)d_out;

    const int N = in_sizes[0] / D_INF;
    const int E = in_sizes[2];
    const int NP64 = ((N + 63) / 64) * 64;
    const int nblk = NP64 / 64;

    char* ws = (char*)d_ws;
    size_t off = 0;
    auto carve = [&](size_t bytes) -> void* {
        void* p = ws + off;
        off = (off + bytes + 255) & ~(size_t)255;
        return p;
    };
    // common buffers
    float* P1  = (float*)carve((size_t)N * HF * 4);
    float* P2  = (float*)carve((size_t)N * HF * 4);
    float* ASC = (float*)carve((size_t)E * 4);
    float* EPS = (float*)carve((size_t)N * 4);
    int*   DEG = (int*)carve((size_t)N * 4);
    int*   OFFS= (int*)carve((size_t)(N + 1) * 4);
    int*   CUR = (int*)carve((size_t)N * 4);
    int*   EL  = (int*)carve((size_t)E * 4);
    const size_t common_end = off;
    // fast-path buffers (blocked layouts)
    short* GHH = (short*)carve((size_t)E * HF * 2);
    short* GHL = (short*)carve((size_t)E * HF * 2);
    short* HHI = (short*)carve((size_t)NP64 * HF * 2);
    short* HLO = (short*)carve((size_t)NP64 * HF * 2);
    short* NFH = (short*)carve((size_t)NP64 * D_INF * 2);
    short* NFL = (short*)carve((size_t)NP64 * D_INF * 2);
    short* WHI = (short*)carve((size_t)LF * 3 * HF * HF * 2);
    short* WLO = (short*)carve((size_t)LF * 3 * HF * HF * 2);
    short* EHI = (short*)carve((size_t)LF * HF * HF * 2);
    short* ELO = (short*)carve((size_t)LF * HF * HF * 2);
    short* WNH = (short*)carve((size_t)D_INF * HF * 2);
    short* WNL = (short*)carve((size_t)D_INF * HF * 2);
    const bool fast = (off <= ws_size) && (E % 64 == 0);

    // CSR build
    hipMemsetAsync(DEG, 0, (size_t)N * 4, stream);
    hist_kernel<<<(E + 255) / 256, 256, 0, stream>>>(dst, DEG, E);
    scan_kernel<<<1, 1024, 0, stream>>>(DEG, OFFS, CUR, N);
    fill_kernel<<<(E + 255) / 256, 256, 0, stream>>>(dst, CUR, EL, E);

    if (fast) {
        // one-time conversions / splits
        conv_aw1_kernel<<<(LF * 3 * HF * HF + 255) / 256, 256, 0, stream>>>(a_w1, WHI, WLO);
        conv_epsw1_kernel<<<(LF * HF * HF + 255) / 256, 256, 0, stream>>>(eps_w1, EHI, ELO);
        conv_wn_kernel<<<(D_INF * HF + 255) / 256, 256, 0, stream>>>(Wn_w, WNH, WNL);
        split_blocked_kernel<<<512, 256, 0, stream>>>(node_feats, NFH, NFL, N, D_INF, 4);
        split_blocked_kernel<<<2048, 256, 0, stream>>>(gh, GHH, GHL, E, HF, 5);

        // input projection -> outs[0]
        proj_mfma_kernel<<<nblk, 256, 0, stream>>>(NFH, NFL, WNH, WNL, Wn_b, out, N);

        for (int l = 0; l < LF; l++) {
            const float* h  = out + (size_t)l * N * HF;
            float*       hn = out + (size_t)(l + 1) * N * HF;
            const float* b1 = a_b1 + (size_t)l * HF;
            const float* w2 = a_w2 + (size_t)l * HF;
            const float* b2 = a_b2 + l;

            split_blocked_kernel<<<1024, 256, 0, stream>>>(h, HHI, HLO, N, HF, 5);

            node_mfma_kernel<<<dim3(nblk, 3), 256, 0, stream>>>(
                HHI, HLO,
                WHI + (size_t)l * 3 * 65536, WLO + (size_t)l * 3 * 65536,
                EHI + (size_t)l * 65536, ELO + (size_t)l * 65536,
                eps_b1 + (size_t)l * HF, eps_w2 + (size_t)l * HF, eps_b2 + l,
                P1, P2, EPS, N);

            edge_mfma2_kernel<<<E / 64, 256, 0, stream>>>(
                GHH, GHL,
                WHI + (size_t)(l * 3 + 2) * 65536, WLO + (size_t)(l * 3 + 2) * 65536,
                b1, w2, b2, P1, P2, src, dst, ASC);

            node_agg_update_kernel<<<(N + 3) / 4, 256, 0, stream>>>(
                ASC, OFFS, EL, src, h, gh, EPS, hn, N);
        }
    } else {
        // fallback = validated round-3 path
        size_t foff = common_end;
        auto fcarve = [&](size_t bytes) -> void* {
            void* p = ws + foff;
            foff = (foff + bytes + 255) & ~(size_t)255;
            return p;
        };
        short* WhiT = (short*)fcarve((size_t)LF * HF * HF * 2);
        short* WloT = (short*)fcarve((size_t)LF * HF * HF * 2);
        const bool mf = (foff <= ws_size) && (E % 64 == 0);
        if (mf)
            conv_w1cT_kernel<<<(LF * HF * HF + 255) / 256, 256, 0, stream>>>(a_w1, WhiT, WloT);

        dim3 gg((N + 63) / 64, HF / 64);
        gemm_f32<<<gg, 256, 0, stream>>>(node_feats, Wn_w, Wn_b, out, N, D_INF, HF);

        const int egrid = (E + 63) / 64;
        const int ngrid = (N + 63) / 64;
        for (int l = 0; l < LF; l++) {
            const float* h  = out + (size_t)l * N * HF;
            float*       hn = out + (size_t)(l + 1) * N * HF;
            const float* W1  = a_w1 + (size_t)l * 3 * HF * HF;
            const float* W1a = W1;
            const float* W1b = W1 + (size_t)HF * HF;
            const float* W1c = W1 + (size_t)2 * HF * HF;
            const float* b1  = a_b1 + (size_t)l * HF;
            const float* w2  = a_w2 + (size_t)l * HF;
            const float* b2  = a_b2 + l;

            gemm_f32<<<gg, 256, 0, stream>>>(h, W1a, nullptr, P1, N, HF, HF);
            gemm_f32<<<gg, 256, 0, stream>>>(h, W1b, nullptr, P2, N, HF, HF);

            if (mf) {
                edge_mfma_kernel<<<E / 64, 256, 0, stream>>>(
                    gh, WhiT + (size_t)l * HF * HF, WloT + (size_t)l * HF * HF,
                    b1, w2, b2, P1, P2, src, dst, ASC);
            } else {
                mlp_score_kernel<<<egrid, 256, 0, stream>>>(
                    gh, W1c, b1, w2, b2, P1, P2, src, dst, ASC, E, HF);
            }

            mlp_score_kernel<<<ngrid, 256, 0, stream>>>(
                h, eps_w1 + (size_t)l * HF * HF, eps_b1 + (size_t)l * HF,
                eps_w2 + (size_t)l * HF, eps_b2 + l,
                nullptr, nullptr, nullptr, nullptr, EPS, N, HF);

            node_agg_update_kernel<<<(N + 3) / 4, 256, 0, stream>>>(
                ASC, OFFS, EL, src, h, gh, EPS, hn, N);
        }
    }
}